// Round 4
// baseline (521.021 us; speedup 1.0000x reference)
//
#include <hip/hip_runtime.h>
#include <hip/hip_bf16.h>

// ---------------------------------------------------------------------------
// OutliersQLinearColumn: out = x @ w^T + bias
// Round 4: 8-phase 256x256 bf16 GEMM, 32x32x16 MFMA, reads pipelined one
// phase ahead (double-buffered fragment registers), 1 barrier/phase.
// LDS sub-tiles [256][32] bf16, slot-XOR swizzle (R3, conflict-free).
// ---------------------------------------------------------------------------

typedef __attribute__((ext_vector_type(8))) __bf16 bf16x8;
typedef __attribute__((ext_vector_type(16))) float f32x16;
typedef unsigned short us4 __attribute__((ext_vector_type(4)));
typedef unsigned short us8 __attribute__((ext_vector_type(8)));

__device__ inline unsigned short f2bf(float f) {
    unsigned u = __float_as_uint(f);
    unsigned r = (u + 0x7FFFu + ((u >> 16) & 1u)) >> 16;  // RNE
    return (unsigned short)r;
}

// ---------------------------------------------------------------------------
__global__ void init_colmap_kernel(int* __restrict__ cm, int IC) {
    int i = blockIdx.x * 256 + threadIdx.x;
    if (i < IC) cm[i] = -1;
}

__global__ void scatter_colmap_kernel(const int* __restrict__ idx,
                                      int* __restrict__ cm, int n) {
    int j = blockIdx.x * 256 + threadIdx.x;
    if (j < n) atomicMax(&cm[idx[j]], j);
}

// ---------------------------------------------------------------------------
__global__ void quant_weight_kernel(const float* __restrict__ w,
                                    const float* __restrict__ ow,
                                    const int* __restrict__ cm,
                                    unsigned short* __restrict__ wq,
                                    int IC, int n_out) {
    __shared__ float red[8];
    const int o = blockIdx.x;
    const int t = threadIdx.x;
    const int lane = t & 63, wid = t >> 6;

    const float4* row4 = (const float4*)(w + (size_t)o * IC);
    float4 v[4];
    float s = 0.f;
#pragma unroll
    for (int j = 0; j < 4; ++j) {
        v[j] = row4[t + j * 256];
        s += v[j].x + v[j].y + v[j].z + v[j].w;
    }
#pragma unroll
    for (int off = 32; off; off >>= 1) s += __shfl_down(s, off);
    if (lane == 0) red[wid] = s;
    __syncthreads();
    const float mean = (red[0] + red[1] + red[2] + red[3]) / (float)IC;

    float a = 0.f;
#pragma unroll
    for (int j = 0; j < 4; ++j)
        a += fabsf(v[j].x - mean) + fabsf(v[j].y - mean) +
             fabsf(v[j].z - mean) + fabsf(v[j].w - mean);
#pragma unroll
    for (int off = 32; off; off >>= 1) a += __shfl_down(a, off);
    if (lane == 0) red[4 + wid] = a;
    __syncthreads();
    const float scale = (red[4] + red[5] + red[6] + red[7]) / (float)IC;

    const size_t base = (size_t)o * IC;
    const float* owr = ow + (size_t)o * n_out;
#pragma unroll
    for (int j = 0; j < 4; ++j) {
        const int c0 = (t + j * 256) * 4;
        float ee[4] = {v[j].x, v[j].y, v[j].z, v[j].w};
        us4 q4;
#pragma unroll
        for (int ei = 0; ei < 4; ++ei) {
            float c = ee[ei] - mean;
            float q = c > 0.f ? scale : (c < 0.f ? -scale : 0.f);
            int m = cm[c0 + ei];
            if (m >= 0) q = owr[m];
            q4[ei] = f2bf(q);
        }
        *(us4*)&wq[base + c0] = q4;
    }
}

// ---------------------------------------------------------------------------
__global__ void cast_x_kernel(const float4* __restrict__ x4,
                              us8* __restrict__ xb, long n8) {
    long i = (long)blockIdx.x * blockDim.x + threadIdx.x;
    const long stride = (long)gridDim.x * blockDim.x;
    for (; i < n8; i += stride) {
        float4 a = x4[i * 2], b = x4[i * 2 + 1];
        us8 o;
        o[0] = f2bf(a.x); o[1] = f2bf(a.y); o[2] = f2bf(a.z); o[3] = f2bf(a.w);
        o[4] = f2bf(b.x); o[5] = f2bf(b.y); o[6] = f2bf(b.z); o[7] = f2bf(b.w);
        xb[i] = o;
    }
}

// ---------------------------------------------------------------------------
// GEMM: C[M,N] = A[M,K] * B[N,K]^T + bias.  512 thr = 8 waves (2M x 4N),
// per-wave 128x64 = 4(mi) x 2(ni) frags of 32x32, mfma_f32_32x32x16_bf16.
// LDS: lds[buf2][mat2][kh2][256][32] bf16 (strides 32768/16384/8192 elems).
// Per phase: STAGE ; [vmcnt(4)] ; s_barrier ; issue NEXT phase's ds_reads ;
//            sched_barrier ; setprio(1) ; 8 MFMA ; setprio(0).
// ---------------------------------------------------------------------------
#define BK 64

#define GLDS(src, dst) __builtin_amdgcn_global_load_lds( \
    (const __attribute__((address_space(1))) void*)(src), \
    (__attribute__((address_space(3))) void*)(dst), 16, 0, 0)

#define STAGE(MAT, KHS, bufS, kn) do {                                        \
    const unsigned short* gsrc_ = (MAT) ? Bblk : Ablk;                        \
    _Pragma("unroll")                                                         \
    for (int rr_ = 0; rr_ < 2; ++rr_) {                                       \
      GLDS(gsrc_ + (size_t)(rr_ * 128 + stg_row) * K + (kn) + (KHS) * 32 + stg_col, \
           &lds[(bufS) * 32768 + (MAT) * 16384 + (KHS) * 8192 +               \
                (rr_ * 128 + wid * 16) * 32]);                                \
    } } while (0)

// A-fragment reads (4 x ds_read_b128) for fragment-half FH, k-half KH, buf B_
#define RDA(AF, FH, KH, B_) do {                                              \
    const unsigned short* pa_ = &lds[(B_) * 32768 + (KH) * 8192];             \
    AF[0] = *(const bf16x8*)&pa_[(wr * 128 + ((FH) * 2 + 0) * 32 + l31) * 32 + sl0]; \
    AF[1] = *(const bf16x8*)&pa_[(wr * 128 + ((FH) * 2 + 0) * 32 + l31) * 32 + sl1]; \
    AF[2] = *(const bf16x8*)&pa_[(wr * 128 + ((FH) * 2 + 1) * 32 + l31) * 32 + sl0]; \
    AF[3] = *(const bf16x8*)&pa_[(wr * 128 + ((FH) * 2 + 1) * 32 + l31) * 32 + sl1]; \
  } while (0)

// B-fragment reads (4 x ds_read_b128) for k-half KH, buf B_
#define RDB(BF, KH, B_) do {                                                  \
    const unsigned short* pb_ = &lds[(B_) * 32768 + 16384 + (KH) * 8192];     \
    BF[0] = *(const bf16x8*)&pb_[(wc * 64 +  0 + l31) * 32 + sl0];            \
    BF[1] = *(const bf16x8*)&pb_[(wc * 64 +  0 + l31) * 32 + sl1];            \
    BF[2] = *(const bf16x8*)&pb_[(wc * 64 + 32 + l31) * 32 + sl0];            \
    BF[3] = *(const bf16x8*)&pb_[(wc * 64 + 32 + l31) * 32 + sl1];            \
  } while (0)

// 8 MFMA for fragment-half FH (ks0 quartet then ks1 quartet)
#define MM(AF, BF, FH) do {                                                   \
    acc[(FH)*2+0][0] = __builtin_amdgcn_mfma_f32_32x32x16_bf16(AF[0], BF[0], acc[(FH)*2+0][0], 0, 0, 0); \
    acc[(FH)*2+0][1] = __builtin_amdgcn_mfma_f32_32x32x16_bf16(AF[0], BF[2], acc[(FH)*2+0][1], 0, 0, 0); \
    acc[(FH)*2+1][0] = __builtin_amdgcn_mfma_f32_32x32x16_bf16(AF[2], BF[0], acc[(FH)*2+1][0], 0, 0, 0); \
    acc[(FH)*2+1][1] = __builtin_amdgcn_mfma_f32_32x32x16_bf16(AF[2], BF[2], acc[(FH)*2+1][1], 0, 0, 0); \
    acc[(FH)*2+0][0] = __builtin_amdgcn_mfma_f32_32x32x16_bf16(AF[1], BF[1], acc[(FH)*2+0][0], 0, 0, 0); \
    acc[(FH)*2+0][1] = __builtin_amdgcn_mfma_f32_32x32x16_bf16(AF[1], BF[3], acc[(FH)*2+0][1], 0, 0, 0); \
    acc[(FH)*2+1][0] = __builtin_amdgcn_mfma_f32_32x32x16_bf16(AF[3], BF[1], acc[(FH)*2+1][0], 0, 0, 0); \
    acc[(FH)*2+1][1] = __builtin_amdgcn_mfma_f32_32x32x16_bf16(AF[3], BF[3], acc[(FH)*2+1][1], 0, 0, 0); \
  } while (0)

// Phase: stage one half-tile, optional vmcnt(4), barrier, issue next reads,
// fence, MFMA current sets.
#define PH(AF, BF, FH, STMAT, STKH, VM, bufS, kn, RDNEXT) do {                \
    STAGE(STMAT, STKH, bufS, kn);                                             \
    if (VM) asm volatile("s_waitcnt vmcnt(4)" ::: "memory");                  \
    __builtin_amdgcn_s_barrier();                                             \
    RDNEXT;                                                                   \
    __builtin_amdgcn_sched_barrier(0);                                        \
    __builtin_amdgcn_s_setprio(1);                                            \
    MM(AF, BF, FH);                                                           \
    __builtin_amdgcn_s_setprio(0);                                            \
  } while (0)

__global__ __launch_bounds__(512, 2) void gemm_8phase_kernel(
    const unsigned short* __restrict__ A,   // [M,K] bf16 bits
    const unsigned short* __restrict__ B,   // [N,K] bf16 bits
    const float* __restrict__ bias,         // [N]
    float* __restrict__ C,                  // [M,N] f32
    int M, int N, int K, int NBN) {
    extern __shared__ unsigned short lds[];  // 131072 B

    const int t = threadIdx.x;
    const int wid = t >> 6, lane = t & 63;
    const int l31 = lane & 31;
    const int hi = lane >> 5;                 // k-half-of-16 selector
    const int tt_ = (l31 >> 1) & 3;           // row swizzle term
    // physical 16B-slot offsets (elements) for ks=0,1: slot=(ks*2+hi)^t
    const int sl0 = (((0 * 2 + hi) ^ tt_) & 3) * 8;
    const int sl1 = (((1 * 2 + hi) ^ tt_) & 3) * 8;
    const int wr = wid >> 2;                  // 0..1  (M half)
    const int wc = wid & 3;                   // 0..3  (N quarter)
    const int stg_row = wid * 16 + (lane >> 2);
    const int stg_col = (((lane & 3) ^ ((lane >> 3) & 3)) & 3) * 8;

    // bijective XCD swizzle
    const int nwg = gridDim.x;
    const int bid = blockIdx.x;
    const int q = nwg >> 3, r = nwg & 7;
    const int xcd = bid & 7, off = bid >> 3;
    const int swz = (xcd < r ? xcd * (q + 1) : r * (q + 1) + (xcd - r) * q) + off;
    const int bm = swz / NBN, bn = swz % NBN;

    const unsigned short* Ablk = A + (size_t)(bm * 256) * K;
    const unsigned short* Bblk = B + (size_t)(bn * 256) * K;

    f32x16 acc[4][2] = {};
    bf16x8 afA[4], afB[4], bfA[4], bfB[4];

    // ---- prologue: stage tile0 into buf0; wait kh0; issue reads for p=0 ----
    STAGE(0, 0, 0, 0);
    STAGE(1, 0, 0, 0);
    STAGE(0, 1, 0, 0);
    STAGE(1, 1, 0, 0);
    asm volatile("s_waitcnt vmcnt(4)" ::: "memory");
    __builtin_amdgcn_s_barrier();
    RDA(afA, 0, 0, 0);
    RDB(bfA, 0, 0);
    __builtin_amdgcn_sched_barrier(0);

    const int NT = K / BK;                    // 64 (even)
    for (int tt = 0; tt < NT; tt += 2) {
        const int kn1 = (tt + 1) * BK;
        const int kn2 = (tt + 2 < NT) ? (tt + 2) * BK : 0;  // dead stage at end
        // p=0..3: read buf0 (tile tt), stage tile tt+1 -> buf1
        PH(afA, bfA, 0, 0, 0, false, 1, kn1, RDA(afB, 1, 0, 0));
        PH(afB, bfA, 1, 1, 0, true,  1, kn1, { RDA(afA, 0, 1, 0); RDB(bfB, 1, 0); });
        PH(afA, bfB, 0, 0, 1, false, 1, kn1, RDA(afB, 1, 1, 0));
        PH(afB, bfB, 1, 1, 1, true,  1, kn1, { RDA(afA, 0, 0, 1); RDB(bfA, 0, 1); });
        // p=4..7: read buf1 (tile tt+1), stage tile tt+2 -> buf0
        PH(afA, bfA, 0, 0, 0, false, 0, kn2, RDA(afB, 1, 0, 1));
        PH(afB, bfA, 1, 1, 0, true,  0, kn2, { RDA(afA, 0, 1, 1); RDB(bfB, 1, 1); });
        PH(afA, bfB, 0, 0, 1, false, 0, kn2, RDA(afB, 1, 1, 1));
        PH(afB, bfB, 1, 1, 1, true,  0, kn2, { RDA(afA, 0, 0, 0); RDB(bfA, 0, 0); });
    }

    // ---- epilogue: bias + store ----
    // 32x32 C/D layout: col = lane&31, row = (reg&3) + 8*(reg>>2) + 4*(lane>>5)
    float bv[2];
#pragma unroll
    for (int ni = 0; ni < 2; ++ni)
        bv[ni] = bias[bn * 256 + wc * 64 + ni * 32 + l31];

    const int hi4 = hi * 4;
#pragma unroll
    for (int mi = 0; mi < 4; ++mi) {
#pragma unroll
        for (int ni = 0; ni < 2; ++ni) {
#pragma unroll
            for (int reg = 0; reg < 16; ++reg) {
                const int row = bm * 256 + wr * 128 + mi * 32 +
                                (reg & 3) + 8 * (reg >> 2) + hi4;
                C[(size_t)row * N + bn * 256 + wc * 64 + ni * 32 + l31] =
                    acc[mi][ni][reg] + bv[ni];
            }
        }
    }
}

// ---------------------------------------------------------------------------
extern "C" void kernel_launch(void* const* d_in, const int* in_sizes, int n_in,
                              void* d_out, int out_size, void* d_ws, size_t ws_size,
                              hipStream_t stream) {
    const float* x      = (const float*)d_in[0];
    const float* weight = (const float*)d_in[1];
    const float* bias   = (const float*)d_in[2];
    const float* ow     = (const float*)d_in[3];
    const int*   idx    = (const int*)d_in[4];

    const int OC    = in_sizes[2];
    const int n_out = in_sizes[4];
    const int IC    = in_sizes[1] / OC;
    const int M     = in_sizes[0] / IC;
    float* out = (float*)d_out;

    char* ws = (char*)d_ws;
    unsigned short* wq = (unsigned short*)ws;                              // OC*IC bf16
    unsigned short* xb = (unsigned short*)(ws + (size_t)OC * IC * 2);      // M*IC bf16
    int* cm = (int*)(ws + (size_t)OC * IC * 2 + (size_t)M * IC * 2);       // IC ints

    init_colmap_kernel<<<(IC + 255) / 256, 256, 0, stream>>>(cm, IC);
    scatter_colmap_kernel<<<(n_out + 255) / 256, 256, 0, stream>>>(idx, cm, n_out);
    quant_weight_kernel<<<OC, 256, 0, stream>>>(weight, ow, cm, wq, IC, n_out);

    const long n8 = (long)M * IC / 8;
    cast_x_kernel<<<2048, 256, 0, stream>>>((const float4*)x, (us8*)xb, n8);

    hipFuncSetAttribute((const void*)gemm_8phase_kernel,
                        hipFuncAttributeMaxDynamicSharedMemorySize, 131072);
    const int NBM = M / 256, NBN = OC / 256;
    gemm_8phase_kernel<<<dim3(NBM * NBN), dim3(512), 131072, stream>>>(
        xb, wq, bias, out, M, OC, IC, NBN);
}

// Round 5
// 311.004 us; speedup vs baseline: 1.6753x; 1.6753x over previous
//
#include <hip/hip_runtime.h>
#include <hip/hip_bf16.h>

// ---------------------------------------------------------------------------
// OutliersQLinearColumn: out = x @ w^T + bias
// Round 5: R3 skeleton (8-phase 256x256, 2 barriers/phase, vmcnt(4) fences,
// slot-XOR LDS swizzle) + 32x32x16 MFMA (single-buffered frags, 32 VGPR)
// + compiler-scheduled LDS reads (no forced lgkmcnt(0)/sched_barrier).
// ---------------------------------------------------------------------------

typedef __attribute__((ext_vector_type(8))) __bf16 bf16x8;
typedef __attribute__((ext_vector_type(16))) float f32x16;
typedef unsigned short us4 __attribute__((ext_vector_type(4)));
typedef unsigned short us8 __attribute__((ext_vector_type(8)));

__device__ inline unsigned short f2bf(float f) {
    unsigned u = __float_as_uint(f);
    unsigned r = (u + 0x7FFFu + ((u >> 16) & 1u)) >> 16;  // RNE
    return (unsigned short)r;
}

// ---------------------------------------------------------------------------
__global__ void init_colmap_kernel(int* __restrict__ cm, int IC) {
    int i = blockIdx.x * 256 + threadIdx.x;
    if (i < IC) cm[i] = -1;
}

__global__ void scatter_colmap_kernel(const int* __restrict__ idx,
                                      int* __restrict__ cm, int n) {
    int j = blockIdx.x * 256 + threadIdx.x;
    if (j < n) atomicMax(&cm[idx[j]], j);
}

// ---------------------------------------------------------------------------
__global__ void quant_weight_kernel(const float* __restrict__ w,
                                    const float* __restrict__ ow,
                                    const int* __restrict__ cm,
                                    unsigned short* __restrict__ wq,
                                    int IC, int n_out) {
    __shared__ float red[8];
    const int o = blockIdx.x;
    const int t = threadIdx.x;
    const int lane = t & 63, wid = t >> 6;

    const float4* row4 = (const float4*)(w + (size_t)o * IC);
    float4 v[4];
    float s = 0.f;
#pragma unroll
    for (int j = 0; j < 4; ++j) {
        v[j] = row4[t + j * 256];
        s += v[j].x + v[j].y + v[j].z + v[j].w;
    }
#pragma unroll
    for (int off = 32; off; off >>= 1) s += __shfl_down(s, off);
    if (lane == 0) red[wid] = s;
    __syncthreads();
    const float mean = (red[0] + red[1] + red[2] + red[3]) / (float)IC;

    float a = 0.f;
#pragma unroll
    for (int j = 0; j < 4; ++j)
        a += fabsf(v[j].x - mean) + fabsf(v[j].y - mean) +
             fabsf(v[j].z - mean) + fabsf(v[j].w - mean);
#pragma unroll
    for (int off = 32; off; off >>= 1) a += __shfl_down(a, off);
    if (lane == 0) red[4 + wid] = a;
    __syncthreads();
    const float scale = (red[4] + red[5] + red[6] + red[7]) / (float)IC;

    const size_t base = (size_t)o * IC;
    const float* owr = ow + (size_t)o * n_out;
#pragma unroll
    for (int j = 0; j < 4; ++j) {
        const int c0 = (t + j * 256) * 4;
        float ee[4] = {v[j].x, v[j].y, v[j].z, v[j].w};
        us4 q4;
#pragma unroll
        for (int ei = 0; ei < 4; ++ei) {
            float c = ee[ei] - mean;
            float q = c > 0.f ? scale : (c < 0.f ? -scale : 0.f);
            int m = cm[c0 + ei];
            if (m >= 0) q = owr[m];
            q4[ei] = f2bf(q);
        }
        *(us4*)&wq[base + c0] = q4;
    }
}

// ---------------------------------------------------------------------------
__global__ void cast_x_kernel(const float4* __restrict__ x4,
                              us8* __restrict__ xb, long n8) {
    long i = (long)blockIdx.x * blockDim.x + threadIdx.x;
    const long stride = (long)gridDim.x * blockDim.x;
    for (; i < n8; i += stride) {
        float4 a = x4[i * 2], b = x4[i * 2 + 1];
        us8 o;
        o[0] = f2bf(a.x); o[1] = f2bf(a.y); o[2] = f2bf(a.z); o[3] = f2bf(a.w);
        o[4] = f2bf(b.x); o[5] = f2bf(b.y); o[6] = f2bf(b.z); o[7] = f2bf(b.w);
        xb[i] = o;
    }
}

// ---------------------------------------------------------------------------
// GEMM: C[M,N] = A[M,K] * B[N,K]^T + bias.  512 thr = 8 waves (2M x 4N),
// per-wave 128x64 = 4(mi) x 2(ni) frags of 32x32, mfma_f32_32x32x16_bf16.
// LDS: lds[buf2][mat2][kh2][256][32] bf16 (strides 32768/16384/8192 elems),
// slot-XOR swizzle: physical 16B-slot = logical ^ ((row>>1)&3).
// Phase (FH,KH): { RDA [+RDB] ; STAGE ; [vmcnt(4)] ; barrier ;
//                  setprio(1) ; 8 MFMA ; setprio(0) ; barrier }
// No forced lgkmcnt(0): compiler emits counted lgkm waits per MFMA operand.
// ---------------------------------------------------------------------------
#define BK 64

#define GLDS(src, dst) __builtin_amdgcn_global_load_lds( \
    (const __attribute__((address_space(1))) void*)(src), \
    (__attribute__((address_space(3))) void*)(dst), 16, 0, 0)

#define STAGE(MAT, KHS, bufS, kn) do {                                        \
    const unsigned short* gsrc_ = (MAT) ? Bblk : Ablk;                        \
    _Pragma("unroll")                                                         \
    for (int rr_ = 0; rr_ < 2; ++rr_) {                                       \
      GLDS(gsrc_ + (size_t)(rr_ * 128 + stg_row) * K + (kn) + (KHS) * 32 + stg_col, \
           &lds[(bufS) * 32768 + (MAT) * 16384 + (KHS) * 8192 +               \
                (rr_ * 128 + wid * 16) * 32]);                                \
    } } while (0)

// A-fragment reads (4 x ds_read_b128) for fragment-half FH, k-half KH, buf B_
#define RDA(AF, FH, KH, B_) do {                                              \
    const unsigned short* pa_ = &lds[(B_) * 32768 + (KH) * 8192];             \
    AF[0] = *(const bf16x8*)&pa_[(wr * 128 + ((FH) * 2 + 0) * 32 + l31) * 32 + sl0]; \
    AF[1] = *(const bf16x8*)&pa_[(wr * 128 + ((FH) * 2 + 0) * 32 + l31) * 32 + sl1]; \
    AF[2] = *(const bf16x8*)&pa_[(wr * 128 + ((FH) * 2 + 1) * 32 + l31) * 32 + sl0]; \
    AF[3] = *(const bf16x8*)&pa_[(wr * 128 + ((FH) * 2 + 1) * 32 + l31) * 32 + sl1]; \
  } while (0)

// B-fragment reads (4 x ds_read_b128) for k-half KH, buf B_
#define RDB(BF, KH, B_) do {                                                  \
    const unsigned short* pb_ = &lds[(B_) * 32768 + 16384 + (KH) * 8192];     \
    BF[0] = *(const bf16x8*)&pb_[(wc * 64 +  0 + l31) * 32 + sl0];            \
    BF[1] = *(const bf16x8*)&pb_[(wc * 64 +  0 + l31) * 32 + sl1];            \
    BF[2] = *(const bf16x8*)&pb_[(wc * 64 + 32 + l31) * 32 + sl0];            \
    BF[3] = *(const bf16x8*)&pb_[(wc * 64 + 32 + l31) * 32 + sl1];            \
  } while (0)

// 8 MFMA for fragment-half FH (ks0 quartet then ks1 quartet)
#define MM(AF, BF, FH) do {                                                   \
    acc[(FH)*2+0][0] = __builtin_amdgcn_mfma_f32_32x32x16_bf16(AF[0], BF[0], acc[(FH)*2+0][0], 0, 0, 0); \
    acc[(FH)*2+0][1] = __builtin_amdgcn_mfma_f32_32x32x16_bf16(AF[0], BF[2], acc[(FH)*2+0][1], 0, 0, 0); \
    acc[(FH)*2+1][0] = __builtin_amdgcn_mfma_f32_32x32x16_bf16(AF[2], BF[0], acc[(FH)*2+1][0], 0, 0, 0); \
    acc[(FH)*2+1][1] = __builtin_amdgcn_mfma_f32_32x32x16_bf16(AF[2], BF[2], acc[(FH)*2+1][1], 0, 0, 0); \
    acc[(FH)*2+0][0] = __builtin_amdgcn_mfma_f32_32x32x16_bf16(AF[1], BF[1], acc[(FH)*2+0][0], 0, 0, 0); \
    acc[(FH)*2+0][1] = __builtin_amdgcn_mfma_f32_32x32x16_bf16(AF[1], BF[3], acc[(FH)*2+0][1], 0, 0, 0); \
    acc[(FH)*2+1][0] = __builtin_amdgcn_mfma_f32_32x32x16_bf16(AF[3], BF[1], acc[(FH)*2+1][0], 0, 0, 0); \
    acc[(FH)*2+1][1] = __builtin_amdgcn_mfma_f32_32x32x16_bf16(AF[3], BF[3], acc[(FH)*2+1][1], 0, 0, 0); \
  } while (0)

// Phase: reads (in-phase, single-buffered) ; stage ; optional vmcnt fence ;
// barrier ; MFMA ; barrier.
#define PH(FH, RDB_TOO, KH, STMAT, STKH, VM, bufR, bufS, kn) do {             \
    RDA(afr, FH, KH, bufR);                                                   \
    if (RDB_TOO) RDB(bfr, KH, bufR);                                          \
    STAGE(STMAT, STKH, bufS, kn);                                             \
    if (VM) asm volatile("s_waitcnt vmcnt(4)" ::: "memory");                  \
    __builtin_amdgcn_s_barrier();                                             \
    __builtin_amdgcn_s_setprio(1);                                            \
    MM(afr, bfr, FH);                                                         \
    __builtin_amdgcn_s_setprio(0);                                            \
    __builtin_amdgcn_s_barrier();                                             \
  } while (0)

// One K-tile = 4 phases (FH x KH). Stages the NEXT tile (k-offset kn) into
// bufS. vmcnt(4) at P1 (drains prev tile's kh1 -> readable in P2) and P3
// (drains next tile's kh0 -> readable in next P0). Never 0 in the loop.
#define KTILE(bufR, bufS, kn) do {                                            \
    PH(0, true,  0, 0, 0, false, bufR, bufS, kn);                             \
    PH(1, false, 0, 1, 0, true,  bufR, bufS, kn);                             \
    PH(0, true,  1, 0, 1, false, bufR, bufS, kn);                             \
    PH(1, false, 1, 1, 1, true,  bufR, bufS, kn);                             \
  } while (0)

__global__ __launch_bounds__(512, 2) void gemm_8phase_kernel(
    const unsigned short* __restrict__ A,   // [M,K] bf16 bits
    const unsigned short* __restrict__ B,   // [N,K] bf16 bits
    const float* __restrict__ bias,         // [N]
    float* __restrict__ C,                  // [M,N] f32
    int M, int N, int K, int NBN) {
    extern __shared__ unsigned short lds[];  // 131072 B

    const int t = threadIdx.x;
    const int wid = t >> 6, lane = t & 63;
    const int l31 = lane & 31;
    const int hi = lane >> 5;                 // k-sub-slice selector
    const int tt_ = (l31 >> 1) & 3;           // row swizzle term
    // physical 16B-slot offsets (elements) for ks=0,1: slot=(ks*2+hi)^tt_
    const int sl0 = (((0 * 2 + hi) ^ tt_) & 3) * 8;
    const int sl1 = (((1 * 2 + hi) ^ tt_) & 3) * 8;
    const int wr = wid >> 2;                  // 0..1  (M half)
    const int wc = wid & 3;                   // 0..3  (N quarter)
    const int stg_row = wid * 16 + (lane >> 2);
    const int stg_col = (((lane & 3) ^ ((lane >> 3) & 3)) & 3) * 8;

    // bijective XCD swizzle
    const int nwg = gridDim.x;
    const int bid = blockIdx.x;
    const int q = nwg >> 3, r = nwg & 7;
    const int xcd = bid & 7, off = bid >> 3;
    const int swz = (xcd < r ? xcd * (q + 1) : r * (q + 1) + (xcd - r) * q) + off;
    const int bm = swz / NBN, bn = swz % NBN;

    const unsigned short* Ablk = A + (size_t)(bm * 256) * K;
    const unsigned short* Bblk = B + (size_t)(bn * 256) * K;

    f32x16 acc[4][2] = {};
    bf16x8 afr[4], bfr[4];

    // ---- prologue: stage tile0 into buf0; wait kh0 halves ----
    STAGE(0, 0, 0, 0);
    STAGE(1, 0, 0, 0);
    STAGE(0, 1, 0, 0);
    STAGE(1, 1, 0, 0);
    asm volatile("s_waitcnt vmcnt(4)" ::: "memory");
    __builtin_amdgcn_s_barrier();

    const int NT = K / BK;                    // 64 (even)
    for (int tt = 0; tt < NT; tt += 2) {
        const int kn1 = (tt + 1) * BK;
        const int kn2 = (tt + 2 < NT) ? (tt + 2) * BK : 0;  // dead stage at end
        KTILE(0, 1, kn1);
        KTILE(1, 0, kn2);
    }

    // ---- epilogue: bias + store ----
    // 32x32 C/D layout: col = lane&31, row = (reg&3) + 8*(reg>>2) + 4*(lane>>5)
    float bv[2];
#pragma unroll
    for (int ni = 0; ni < 2; ++ni)
        bv[ni] = bias[bn * 256 + wc * 64 + ni * 32 + l31];

    const int hi4 = hi * 4;
#pragma unroll
    for (int mi = 0; mi < 4; ++mi) {
#pragma unroll
        for (int ni = 0; ni < 2; ++ni) {
#pragma unroll
            for (int reg = 0; reg < 16; ++reg) {
                const int row = bm * 256 + wr * 128 + mi * 32 +
                                (reg & 3) + 8 * (reg >> 2) + hi4;
                C[(size_t)row * N + bn * 256 + wc * 64 + ni * 32 + l31] =
                    acc[mi][ni][reg] + bv[ni];
            }
        }
    }
}

// ---------------------------------------------------------------------------
extern "C" void kernel_launch(void* const* d_in, const int* in_sizes, int n_in,
                              void* d_out, int out_size, void* d_ws, size_t ws_size,
                              hipStream_t stream) {
    const float* x      = (const float*)d_in[0];
    const float* weight = (const float*)d_in[1];
    const float* bias   = (const float*)d_in[2];
    const float* ow     = (const float*)d_in[3];
    const int*   idx    = (const int*)d_in[4];

    const int OC    = in_sizes[2];
    const int n_out = in_sizes[4];
    const int IC    = in_sizes[1] / OC;
    const int M     = in_sizes[0] / IC;
    float* out = (float*)d_out;

    char* ws = (char*)d_ws;
    unsigned short* wq = (unsigned short*)ws;                              // OC*IC bf16
    unsigned short* xb = (unsigned short*)(ws + (size_t)OC * IC * 2);      // M*IC bf16
    int* cm = (int*)(ws + (size_t)OC * IC * 2 + (size_t)M * IC * 2);       // IC ints

    init_colmap_kernel<<<(IC + 255) / 256, 256, 0, stream>>>(cm, IC);
    scatter_colmap_kernel<<<(n_out + 255) / 256, 256, 0, stream>>>(idx, cm, n_out);
    quant_weight_kernel<<<OC, 256, 0, stream>>>(weight, ow, cm, wq, IC, n_out);

    const long n8 = (long)M * IC / 8;
    cast_x_kernel<<<2048, 256, 0, stream>>>((const float4*)x, (us8*)xb, n8);

    hipFuncSetAttribute((const void*)gemm_8phase_kernel,
                        hipFuncAttributeMaxDynamicSharedMemorySize, 131072);
    const int NBM = M / 256, NBN = OC / 256;
    gemm_8phase_kernel<<<dim3(NBM * NBN), dim3(512), 131072, stream>>>(
        xb, wq, bias, out, M, OC, IC, NBN);
}

// Round 6
// 292.829 us; speedup vs baseline: 1.7793x; 1.0621x over previous
//
#include <hip/hip_runtime.h>
#include <hip/hip_bf16.h>

// ---------------------------------------------------------------------------
// OutliersQLinearColumn: out = x @ w^T + bias
// Round 6: R3's 16x16 MFMA + slot-XOR swizzle (measured 0 conflicts), with a
// DEEPER pipeline: 4 LDS buffers of BK=32 (128 KiB), stage tile t+3 while
// computing tile t, single counted vmcnt(8) per tile (issue-to-wait distance
// ~4-6 phases, fully hiding HBM latency). Phases otherwise identical to R3.
// ---------------------------------------------------------------------------

typedef __attribute__((ext_vector_type(8))) __bf16 bf16x8;
typedef __attribute__((ext_vector_type(4))) float  f32x4;
typedef unsigned short us4 __attribute__((ext_vector_type(4)));
typedef unsigned short us8 __attribute__((ext_vector_type(8)));

__device__ inline unsigned short f2bf(float f) {
    unsigned u = __float_as_uint(f);
    unsigned r = (u + 0x7FFFu + ((u >> 16) & 1u)) >> 16;  // RNE
    return (unsigned short)r;
}

// ---------------------------------------------------------------------------
__global__ void init_colmap_kernel(int* __restrict__ cm, int IC) {
    int i = blockIdx.x * 256 + threadIdx.x;
    if (i < IC) cm[i] = -1;
}

__global__ void scatter_colmap_kernel(const int* __restrict__ idx,
                                      int* __restrict__ cm, int n) {
    int j = blockIdx.x * 256 + threadIdx.x;
    if (j < n) atomicMax(&cm[idx[j]], j);
}

// ---------------------------------------------------------------------------
__global__ void quant_weight_kernel(const float* __restrict__ w,
                                    const float* __restrict__ ow,
                                    const int* __restrict__ cm,
                                    unsigned short* __restrict__ wq,
                                    int IC, int n_out) {
    __shared__ float red[8];
    const int o = blockIdx.x;
    const int t = threadIdx.x;
    const int lane = t & 63, wid = t >> 6;

    const float4* row4 = (const float4*)(w + (size_t)o * IC);
    float4 v[4];
    float s = 0.f;
#pragma unroll
    for (int j = 0; j < 4; ++j) {
        v[j] = row4[t + j * 256];
        s += v[j].x + v[j].y + v[j].z + v[j].w;
    }
#pragma unroll
    for (int off = 32; off; off >>= 1) s += __shfl_down(s, off);
    if (lane == 0) red[wid] = s;
    __syncthreads();
    const float mean = (red[0] + red[1] + red[2] + red[3]) / (float)IC;

    float a = 0.f;
#pragma unroll
    for (int j = 0; j < 4; ++j)
        a += fabsf(v[j].x - mean) + fabsf(v[j].y - mean) +
             fabsf(v[j].z - mean) + fabsf(v[j].w - mean);
#pragma unroll
    for (int off = 32; off; off >>= 1) a += __shfl_down(a, off);
    if (lane == 0) red[4 + wid] = a;
    __syncthreads();
    const float scale = (red[4] + red[5] + red[6] + red[7]) / (float)IC;

    const size_t base = (size_t)o * IC;
    const float* owr = ow + (size_t)o * n_out;
#pragma unroll
    for (int j = 0; j < 4; ++j) {
        const int c0 = (t + j * 256) * 4;
        float ee[4] = {v[j].x, v[j].y, v[j].z, v[j].w};
        us4 q4;
#pragma unroll
        for (int ei = 0; ei < 4; ++ei) {
            float c = ee[ei] - mean;
            float q = c > 0.f ? scale : (c < 0.f ? -scale : 0.f);
            int m = cm[c0 + ei];
            if (m >= 0) q = owr[m];
            q4[ei] = f2bf(q);
        }
        *(us4*)&wq[base + c0] = q4;
    }
}

// ---------------------------------------------------------------------------
__global__ void cast_x_kernel(const float4* __restrict__ x4,
                              us8* __restrict__ xb, long n8) {
    long i = (long)blockIdx.x * blockDim.x + threadIdx.x;
    const long stride = (long)gridDim.x * blockDim.x;
    for (; i < n8; i += stride) {
        float4 a = x4[i * 2], b = x4[i * 2 + 1];
        us8 o;
        o[0] = f2bf(a.x); o[1] = f2bf(a.y); o[2] = f2bf(a.z); o[3] = f2bf(a.w);
        o[4] = f2bf(b.x); o[5] = f2bf(b.y); o[6] = f2bf(b.z); o[7] = f2bf(b.w);
        xb[i] = o;
    }
}

// ---------------------------------------------------------------------------
// GEMM: C[M,N] = A[M,K] * B[N,K]^T + bias.  512 thr = 8 waves (2M x 4N),
// per-wave 128x64 = 8(mi) x 4(ni) frags of 16x16, mfma_f32_16x16x32_bf16.
// LDS: lds[buf4][mat2][256][32] bf16 (strides 16384 / 8192 elems), 128 KiB.
// Slot-XOR swizzle (R3, measured 0 conflicts):
//   physical 16B-slot = logical ^ ((row>>1)&3)
//   read slot  -> (lane>>4) ^ ((lane>>1)&3)
//   stage gsrc -> (lane&3)  ^ ((lane>>3)&3)
// Tile = BK32, 2 phases (FH=0,1). Per phase:
//   { 4|8 ds_read_b128 ; STAGE32 (2 global_load_lds, tile t+3) ;
//     [vmcnt(8) at last phase only] ; s_barrier ; lgkmcnt(0) ; sched_barrier ;
//     setprio(1) ; 16 MFMA ; setprio(0) ; s_barrier }
// vmcnt(8): tiles t+2,t+3 (4 loads each) stay in flight; waits for t+1 whose
// loads were issued ~4-6 phases earlier (>2200 cy) -> never exposed.
// ---------------------------------------------------------------------------
#define GLDS(src, dst) __builtin_amdgcn_global_load_lds( \
    (const __attribute__((address_space(1))) void*)(src), \
    (__attribute__((address_space(3))) void*)(dst), 16, 0, 0)

// Stage matrix MAT (0=A,1=B) of the BK32 tile at k-offset kn into buffer bufS.
#define STAGE32(MAT, bufS, kn) do {                                           \
    const unsigned short* gsrc_ = (MAT) ? Bblk : Ablk;                        \
    _Pragma("unroll")                                                         \
    for (int rr_ = 0; rr_ < 2; ++rr_) {                                       \
      GLDS(gsrc_ + (size_t)(rr_ * 128 + stg_row) * K + (kn) + stg_col,        \
           &lds[(bufS) * 16384 + (MAT) * 8192 + (rr_ * 128 + wid * 16) * 32]);\
    } } while (0)

// A-fragment reads (4 x ds_read_b128) for fragment-half FH from buf B_
#define RDA(AF, FH, B_) do {                                                  \
    const unsigned short* pa_ = &lds[(B_) * 16384];                           \
    _Pragma("unroll")                                                         \
    for (int j_ = 0; j_ < 4; ++j_)                                            \
      AF[j_] = *(const bf16x8*)&pa_[(wr * 128 + ((FH) * 4 + j_) * 16 + l15) * 32 + sl8]; \
  } while (0)

// B-fragment reads (4 x ds_read_b128) from buf B_
#define RDB(BF, B_) do {                                                      \
    const unsigned short* pb_ = &lds[(B_) * 16384 + 8192];                    \
    _Pragma("unroll")                                                         \
    for (int j_ = 0; j_ < 4; ++j_)                                            \
      BF[j_] = *(const bf16x8*)&pb_[(wc * 64 + j_ * 16 + l15) * 32 + sl8];    \
  } while (0)

#define MM16(FH) do {                                                         \
    _Pragma("unroll")                                                         \
    for (int mi_ = 0; mi_ < 4; ++mi_)                                         \
      _Pragma("unroll")                                                       \
      for (int ni_ = 0; ni_ < 4; ++ni_)                                       \
        acc[(FH) * 4 + mi_][ni_] = __builtin_amdgcn_mfma_f32_16x16x32_bf16(   \
            afr[mi_], bfr[ni_], acc[(FH) * 4 + mi_][ni_], 0, 0, 0);           \
  } while (0)

#define PH32(FH, DOBF, STMAT, VM, bufR, bufS, kn) do {                        \
    RDA(afr, FH, bufR);                                                       \
    if (DOBF) RDB(bfr, bufR);                                                 \
    STAGE32(STMAT, bufS, kn);                                                 \
    if (VM) asm volatile("s_waitcnt vmcnt(8)" ::: "memory");                  \
    __builtin_amdgcn_s_barrier();                                             \
    asm volatile("s_waitcnt lgkmcnt(0)" ::: "memory");                        \
    __builtin_amdgcn_sched_barrier(0);                                        \
    __builtin_amdgcn_s_setprio(1);                                            \
    MM16(FH);                                                                 \
    __builtin_amdgcn_s_setprio(0);                                            \
    __builtin_amdgcn_s_barrier();                                             \
  } while (0)

// One BK32 tile: P0 stages A of tile t+3, P1 stages B + counted vmcnt(8).
#define KT32(bufR, bufS, kn) do {                                             \
    PH32(0, true,  0, false, bufR, bufS, kn);                                 \
    PH32(1, false, 1, true,  bufR, bufS, kn);                                 \
  } while (0)

__global__ __launch_bounds__(512, 2) void gemm_8phase_kernel(
    const unsigned short* __restrict__ A,   // [M,K] bf16 bits
    const unsigned short* __restrict__ B,   // [N,K] bf16 bits
    const float* __restrict__ bias,         // [N]
    float* __restrict__ C,                  // [M,N] f32
    int M, int N, int K, int NBN) {
    extern __shared__ unsigned short lds[];  // 131072 B = 4 x 32 KiB buffers

    const int t = threadIdx.x;
    const int wid = t >> 6, lane = t & 63;
    const int l15 = lane & 15;
    const int sl8 = (((lane >> 4) ^ ((lane >> 1) & 3)) & 3) * 8;  // read slot
    const int wr = wid >> 2;                  // 0..1  (M half)
    const int wc = wid & 3;                   // 0..3  (N quarter)
    const int stg_row = wid * 16 + (lane >> 2);
    const int stg_col = (((lane & 3) ^ ((lane >> 3) & 3)) & 3) * 8;

    // bijective XCD swizzle
    const int nwg = gridDim.x;
    const int bid = blockIdx.x;
    const int q = nwg >> 3, r = nwg & 7;
    const int xcd = bid & 7, off = bid >> 3;
    const int swz = (xcd < r ? xcd * (q + 1) : r * (q + 1) + (xcd - r) * q) + off;
    const int bm = swz / NBN, bn = swz % NBN;

    const unsigned short* Ablk = A + (size_t)(bm * 256) * K;
    const unsigned short* Bblk = B + (size_t)(bn * 256) * K;

    f32x4 acc[8][4] = {};
    bf16x8 afr[4], bfr[4];

    // ---- prologue: stage tiles 0,1,2 into bufs 0,1,2; wait tile0 ----
    STAGE32(0, 0, 0);   STAGE32(1, 0, 0);
    STAGE32(0, 1, 32);  STAGE32(1, 1, 32);
    STAGE32(0, 2, 64);  STAGE32(1, 2, 64);
    asm volatile("s_waitcnt vmcnt(8)" ::: "memory");
    __builtin_amdgcn_s_barrier();

    // NT = K/32 = 128 tiles = 32 iterations x 4. During tile t stage t+3.
    for (int it = 0; it < 32; ++it) {
        const int tt = it * 4;
        const int k3 = (tt + 3) * 32;                         // always live
        const int k4 = (tt + 4 < 128) ? (tt + 4) * 32 : 0;    // dead on last
        const int k5 = (tt + 5 < 128) ? (tt + 5) * 32 : 0;
        const int k6 = (tt + 6 < 128) ? (tt + 6) * 32 : 0;
        KT32(0, 3, k3);
        KT32(1, 0, k4);
        KT32(2, 1, k5);
        KT32(3, 2, k6);
    }

    // ---- epilogue: bias + store (C/D: col=lane&15, row=(lane>>4)*4+r) ----
    float bv[4];
#pragma unroll
    for (int ni = 0; ni < 4; ++ni)
        bv[ni] = bias[bn * 256 + wc * 64 + ni * 16 + l15];

    const int crow0 = bm * 256 + wr * 128;
    const int ccol = bn * 256 + wc * 64 + l15;
#pragma unroll
    for (int mi = 0; mi < 8; ++mi) {
#pragma unroll
        for (int rr = 0; rr < 4; ++rr) {
            const int row = crow0 + mi * 16 + (lane >> 4) * 4 + rr;
            float* Crow = C + (size_t)row * N;
#pragma unroll
            for (int ni = 0; ni < 4; ++ni)
                Crow[ccol + ni * 16] = acc[mi][ni][rr] + bv[ni];
        }
    }
}

// ---------------------------------------------------------------------------
extern "C" void kernel_launch(void* const* d_in, const int* in_sizes, int n_in,
                              void* d_out, int out_size, void* d_ws, size_t ws_size,
                              hipStream_t stream) {
    const float* x      = (const float*)d_in[0];
    const float* weight = (const float*)d_in[1];
    const float* bias   = (const float*)d_in[2];
    const float* ow     = (const float*)d_in[3];
    const int*   idx    = (const int*)d_in[4];

    const int OC    = in_sizes[2];
    const int n_out = in_sizes[4];
    const int IC    = in_sizes[1] / OC;
    const int M     = in_sizes[0] / IC;
    float* out = (float*)d_out;

    char* ws = (char*)d_ws;
    unsigned short* wq = (unsigned short*)ws;                              // OC*IC bf16
    unsigned short* xb = (unsigned short*)(ws + (size_t)OC * IC * 2);      // M*IC bf16
    int* cm = (int*)(ws + (size_t)OC * IC * 2 + (size_t)M * IC * 2);       // IC ints

    init_colmap_kernel<<<(IC + 255) / 256, 256, 0, stream>>>(cm, IC);
    scatter_colmap_kernel<<<(n_out + 255) / 256, 256, 0, stream>>>(idx, cm, n_out);
    quant_weight_kernel<<<OC, 256, 0, stream>>>(weight, ow, cm, wq, IC, n_out);

    const long n8 = (long)M * IC / 8;
    cast_x_kernel<<<2048, 256, 0, stream>>>((const float4*)x, (us8*)xb, n8);

    hipFuncSetAttribute((const void*)gemm_8phase_kernel,
                        hipFuncAttributeMaxDynamicSharedMemorySize, 131072);
    const int NBM = M / 256, NBN = OC / 256;
    gemm_8phase_kernel<<<dim3(NBM * NBN), dim3(512), 131072, stream>>>(
        xb, wq, bias, out, M, OC, IC, NBN);
}

// Round 7
// 292.300 us; speedup vs baseline: 1.7825x; 1.0018x over previous
//
#include <hip/hip_runtime.h>
#include <hip/hip_bf16.h>

// ---------------------------------------------------------------------------
// OutliersQLinearColumn: out = x @ w^T + bias
// Round 7: R6 skeleton (16x16 MFMA, slot-XOR swizzle, 4 LDS buffers BK=32,
// vmcnt(8) counted pipeline) with COMPILER-SCHEDULED lgkm waits:
// forced lgkmcnt(0)+sched_barrier(0) removed; RDB issued before RDA so the
// MFMA cluster consumes reads incrementally (counted lgkmcnt per operand).
// ---------------------------------------------------------------------------

typedef __attribute__((ext_vector_type(8))) __bf16 bf16x8;
typedef __attribute__((ext_vector_type(4))) float  f32x4;
typedef unsigned short us4 __attribute__((ext_vector_type(4)));
typedef unsigned short us8 __attribute__((ext_vector_type(8)));

__device__ inline unsigned short f2bf(float f) {
    unsigned u = __float_as_uint(f);
    unsigned r = (u + 0x7FFFu + ((u >> 16) & 1u)) >> 16;  // RNE
    return (unsigned short)r;
}

// ---------------------------------------------------------------------------
__global__ void init_colmap_kernel(int* __restrict__ cm, int IC) {
    int i = blockIdx.x * 256 + threadIdx.x;
    if (i < IC) cm[i] = -1;
}

__global__ void scatter_colmap_kernel(const int* __restrict__ idx,
                                      int* __restrict__ cm, int n) {
    int j = blockIdx.x * 256 + threadIdx.x;
    if (j < n) atomicMax(&cm[idx[j]], j);
}

// ---------------------------------------------------------------------------
__global__ void quant_weight_kernel(const float* __restrict__ w,
                                    const float* __restrict__ ow,
                                    const int* __restrict__ cm,
                                    unsigned short* __restrict__ wq,
                                    int IC, int n_out) {
    __shared__ float red[8];
    const int o = blockIdx.x;
    const int t = threadIdx.x;
    const int lane = t & 63, wid = t >> 6;

    const float4* row4 = (const float4*)(w + (size_t)o * IC);
    float4 v[4];
    float s = 0.f;
#pragma unroll
    for (int j = 0; j < 4; ++j) {
        v[j] = row4[t + j * 256];
        s += v[j].x + v[j].y + v[j].z + v[j].w;
    }
#pragma unroll
    for (int off = 32; off; off >>= 1) s += __shfl_down(s, off);
    if (lane == 0) red[wid] = s;
    __syncthreads();
    const float mean = (red[0] + red[1] + red[2] + red[3]) / (float)IC;

    float a = 0.f;
#pragma unroll
    for (int j = 0; j < 4; ++j)
        a += fabsf(v[j].x - mean) + fabsf(v[j].y - mean) +
             fabsf(v[j].z - mean) + fabsf(v[j].w - mean);
#pragma unroll
    for (int off = 32; off; off >>= 1) a += __shfl_down(a, off);
    if (lane == 0) red[4 + wid] = a;
    __syncthreads();
    const float scale = (red[4] + red[5] + red[6] + red[7]) / (float)IC;

    const size_t base = (size_t)o * IC;
    const float* owr = ow + (size_t)o * n_out;
#pragma unroll
    for (int j = 0; j < 4; ++j) {
        const int c0 = (t + j * 256) * 4;
        float ee[4] = {v[j].x, v[j].y, v[j].z, v[j].w};
        us4 q4;
#pragma unroll
        for (int ei = 0; ei < 4; ++ei) {
            float c = ee[ei] - mean;
            float q = c > 0.f ? scale : (c < 0.f ? -scale : 0.f);
            int m = cm[c0 + ei];
            if (m >= 0) q = owr[m];
            q4[ei] = f2bf(q);
        }
        *(us4*)&wq[base + c0] = q4;
    }
}

// ---------------------------------------------------------------------------
__global__ void cast_x_kernel(const float4* __restrict__ x4,
                              us8* __restrict__ xb, long n8) {
    long i = (long)blockIdx.x * blockDim.x + threadIdx.x;
    const long stride = (long)gridDim.x * blockDim.x;
    for (; i < n8; i += stride) {
        float4 a = x4[i * 2], b = x4[i * 2 + 1];
        us8 o;
        o[0] = f2bf(a.x); o[1] = f2bf(a.y); o[2] = f2bf(a.z); o[3] = f2bf(a.w);
        o[4] = f2bf(b.x); o[5] = f2bf(b.y); o[6] = f2bf(b.z); o[7] = f2bf(b.w);
        xb[i] = o;
    }
}

// ---------------------------------------------------------------------------
// GEMM: C[M,N] = A[M,K] * B[N,K]^T + bias.  512 thr = 8 waves (2M x 4N),
// per-wave 128x64 = 8(mi) x 4(ni) frags of 16x16, mfma_f32_16x16x32_bf16.
// LDS: lds[buf4][mat2][256][32] bf16 (strides 16384 / 8192 elems), 128 KiB.
// Slot-XOR swizzle (R3/R6, measured 0 conflicts):
//   physical 16B-slot = logical ^ ((row>>1)&3)
//   read slot  -> (lane>>4) ^ ((lane>>1)&3)
//   stage gsrc -> (lane&3)  ^ ((lane>>3)&3)
// Tile = BK32, 2 phases (FH=0,1). Per phase:
//   { RDB(4)|- ; RDA(4) ; STAGE32 (tile t+3) ; [vmcnt(8) last phase] ;
//     s_barrier ; setprio(1) ; 16 MFMA (compiler counted lgkm waits) ;
//     setprio(0) ; s_barrier }
// vmcnt(8): tiles t+2,t+3 (4 loads each) in flight; waits for t+1 whose loads
// were issued ~4-6 phases (>2200 cy) earlier -> never exposed.
// ---------------------------------------------------------------------------
#define GLDS(src, dst) __builtin_amdgcn_global_load_lds( \
    (const __attribute__((address_space(1))) void*)(src), \
    (__attribute__((address_space(3))) void*)(dst), 16, 0, 0)

// Stage matrix MAT (0=A,1=B) of the BK32 tile at k-offset kn into buffer bufS.
#define STAGE32(MAT, bufS, kn) do {                                           \
    const unsigned short* gsrc_ = (MAT) ? Bblk : Ablk;                        \
    _Pragma("unroll")                                                         \
    for (int rr_ = 0; rr_ < 2; ++rr_) {                                       \
      GLDS(gsrc_ + (size_t)(rr_ * 128 + stg_row) * K + (kn) + stg_col,        \
           &lds[(bufS) * 16384 + (MAT) * 8192 + (rr_ * 128 + wid * 16) * 32]);\
    } } while (0)

// A-fragment reads (4 x ds_read_b128) for fragment-half FH from buf B_
#define RDA(AF, FH, B_) do {                                                  \
    const unsigned short* pa_ = &lds[(B_) * 16384];                           \
    _Pragma("unroll")                                                         \
    for (int j_ = 0; j_ < 4; ++j_)                                            \
      AF[j_] = *(const bf16x8*)&pa_[(wr * 128 + ((FH) * 4 + j_) * 16 + l15) * 32 + sl8]; \
  } while (0)

// B-fragment reads (4 x ds_read_b128) from buf B_
#define RDB(BF, B_) do {                                                      \
    const unsigned short* pb_ = &lds[(B_) * 16384 + 8192];                    \
    _Pragma("unroll")                                                         \
    for (int j_ = 0; j_ < 4; ++j_)                                            \
      BF[j_] = *(const bf16x8*)&pb_[(wc * 64 + j_ * 16 + l15) * 32 + sl8];    \
  } while (0)

// 16 MFMA, mi-major: quartet mi needs afr[mi] + bfr[0..3]; with RDB issued
// first, quartet 0 depends on reads 1..5 of 8 and the compiler's counted
// lgkmcnt lets quartets overlap the remaining read completions.
#define MM16(FH) do {                                                         \
    _Pragma("unroll")                                                         \
    for (int mi_ = 0; mi_ < 4; ++mi_)                                         \
      _Pragma("unroll")                                                       \
      for (int ni_ = 0; ni_ < 4; ++ni_)                                       \
        acc[(FH) * 4 + mi_][ni_] = __builtin_amdgcn_mfma_f32_16x16x32_bf16(   \
            afr[mi_], bfr[ni_], acc[(FH) * 4 + mi_][ni_], 0, 0, 0);           \
  } while (0)

#define PH32(FH, DOBF, STMAT, VM, bufR, bufS, kn) do {                        \
    if (DOBF) RDB(bfr, bufR);                                                 \
    RDA(afr, FH, bufR);                                                       \
    STAGE32(STMAT, bufS, kn);                                                 \
    if (VM) asm volatile("s_waitcnt vmcnt(8)" ::: "memory");                  \
    __builtin_amdgcn_s_barrier();                                             \
    __builtin_amdgcn_s_setprio(1);                                            \
    MM16(FH);                                                                 \
    __builtin_amdgcn_s_setprio(0);                                            \
    __builtin_amdgcn_s_barrier();                                             \
  } while (0)

// One BK32 tile: P0 stages A of tile t+3, P1 stages B + counted vmcnt(8).
#define KT32(bufR, bufS, kn) do {                                             \
    PH32(0, true,  0, false, bufR, bufS, kn);                                 \
    PH32(1, false, 1, true,  bufR, bufS, kn);                                 \
  } while (0)

__global__ __launch_bounds__(512, 2) void gemm_8phase_kernel(
    const unsigned short* __restrict__ A,   // [M,K] bf16 bits
    const unsigned short* __restrict__ B,   // [N,K] bf16 bits
    const float* __restrict__ bias,         // [N]
    float* __restrict__ C,                  // [M,N] f32
    int M, int N, int K, int NBN) {
    extern __shared__ unsigned short lds[];  // 131072 B = 4 x 32 KiB buffers

    const int t = threadIdx.x;
    const int wid = t >> 6, lane = t & 63;
    const int l15 = lane & 15;
    const int sl8 = (((lane >> 4) ^ ((lane >> 1) & 3)) & 3) * 8;  // read slot
    const int wr = wid >> 2;                  // 0..1  (M half)
    const int wc = wid & 3;                   // 0..3  (N quarter)
    const int stg_row = wid * 16 + (lane >> 2);
    const int stg_col = (((lane & 3) ^ ((lane >> 3) & 3)) & 3) * 8;

    // bijective XCD swizzle
    const int nwg = gridDim.x;
    const int bid = blockIdx.x;
    const int q = nwg >> 3, r = nwg & 7;
    const int xcd = bid & 7, off = bid >> 3;
    const int swz = (xcd < r ? xcd * (q + 1) : r * (q + 1) + (xcd - r) * q) + off;
    const int bm = swz / NBN, bn = swz % NBN;

    const unsigned short* Ablk = A + (size_t)(bm * 256) * K;
    const unsigned short* Bblk = B + (size_t)(bn * 256) * K;

    f32x4 acc[8][4] = {};
    bf16x8 afr[4], bfr[4];

    // ---- prologue: stage tiles 0,1,2 into bufs 0,1,2; wait tile0 ----
    STAGE32(0, 0, 0);   STAGE32(1, 0, 0);
    STAGE32(0, 1, 32);  STAGE32(1, 1, 32);
    STAGE32(0, 2, 64);  STAGE32(1, 2, 64);
    asm volatile("s_waitcnt vmcnt(8)" ::: "memory");
    __builtin_amdgcn_s_barrier();

    // NT = K/32 = 128 tiles = 32 iterations x 4. During tile t stage t+3.
    for (int it = 0; it < 32; ++it) {
        const int tt = it * 4;
        const int k3 = (tt + 3) * 32;                         // always live
        const int k4 = (tt + 4 < 128) ? (tt + 4) * 32 : 0;    // dead on last
        const int k5 = (tt + 5 < 128) ? (tt + 5) * 32 : 0;
        const int k6 = (tt + 6 < 128) ? (tt + 6) * 32 : 0;
        KT32(0, 3, k3);
        KT32(1, 0, k4);
        KT32(2, 1, k5);
        KT32(3, 2, k6);
    }

    // ---- epilogue: bias + store (C/D: col=lane&15, row=(lane>>4)*4+r) ----
    float bv[4];
#pragma unroll
    for (int ni = 0; ni < 4; ++ni)
        bv[ni] = bias[bn * 256 + wc * 64 + ni * 16 + l15];

    const int crow0 = bm * 256 + wr * 128;
    const int ccol = bn * 256 + wc * 64 + l15;
#pragma unroll
    for (int mi = 0; mi < 8; ++mi) {
#pragma unroll
        for (int rr = 0; rr < 4; ++rr) {
            const int row = crow0 + mi * 16 + (lane >> 4) * 4 + rr;
            float* Crow = C + (size_t)row * N;
#pragma unroll
            for (int ni = 0; ni < 4; ++ni)
                Crow[ccol + ni * 16] = acc[mi][ni][rr] + bv[ni];
        }
    }
}

// ---------------------------------------------------------------------------
extern "C" void kernel_launch(void* const* d_in, const int* in_sizes, int n_in,
                              void* d_out, int out_size, void* d_ws, size_t ws_size,
                              hipStream_t stream) {
    const float* x      = (const float*)d_in[0];
    const float* weight = (const float*)d_in[1];
    const float* bias   = (const float*)d_in[2];
    const float* ow     = (const float*)d_in[3];
    const int*   idx    = (const int*)d_in[4];

    const int OC    = in_sizes[2];
    const int n_out = in_sizes[4];
    const int IC    = in_sizes[1] / OC;
    const int M     = in_sizes[0] / IC;
    float* out = (float*)d_out;

    char* ws = (char*)d_ws;
    unsigned short* wq = (unsigned short*)ws;                              // OC*IC bf16
    unsigned short* xb = (unsigned short*)(ws + (size_t)OC * IC * 2);      // M*IC bf16
    int* cm = (int*)(ws + (size_t)OC * IC * 2 + (size_t)M * IC * 2);       // IC ints

    init_colmap_kernel<<<(IC + 255) / 256, 256, 0, stream>>>(cm, IC);
    scatter_colmap_kernel<<<(n_out + 255) / 256, 256, 0, stream>>>(idx, cm, n_out);
    quant_weight_kernel<<<OC, 256, 0, stream>>>(weight, ow, cm, wq, IC, n_out);

    const long n8 = (long)M * IC / 8;
    cast_x_kernel<<<2048, 256, 0, stream>>>((const float4*)x, (us8*)xb, n8);

    hipFuncSetAttribute((const void*)gemm_8phase_kernel,
                        hipFuncAttributeMaxDynamicSharedMemorySize, 131072);
    const int NBM = M / 256, NBN = OC / 256;
    gemm_8phase_kernel<<<dim3(NBM * NBN), dim3(512), 131072, stream>>>(
        xb, wq, bias, out, M, OC, IC, NBN);
}

// Round 8
// 291.554 us; speedup vs baseline: 1.7870x; 1.0026x over previous
//
#include <hip/hip_runtime.h>
#include <hip/hip_bf16.h>

// ---------------------------------------------------------------------------
// OutliersQLinearColumn: out = x @ w^T + bias
// Round 8: R6/R7 skeleton (16x16 MFMA, slot-XOR swizzle, 4 LDS bufs BK=32)
// + CROSS-PHASE READ PIPELINING: phase p+1's ds_reads issue right after
// phase p's opening barrier and complete under phase p's MFMA window.
// Made safe by the 4-buf pipeline with a deeper drain: vmcnt(4) (only the
// current tile's 4 stages in flight) -> buf(t+1) is valid one tile early.
// Frag sets statically double-buffered (af0/af1 per-phase, bf0/bf1 per-tile).
// Addressing dieted: 4 advancing global pointer pairs + compile-time offsets.
// ---------------------------------------------------------------------------

typedef __attribute__((ext_vector_type(8))) __bf16 bf16x8;
typedef __attribute__((ext_vector_type(4))) float  f32x4;
typedef unsigned short us4 __attribute__((ext_vector_type(4)));
typedef unsigned short us8 __attribute__((ext_vector_type(8)));

__device__ inline unsigned short f2bf(float f) {
    unsigned u = __float_as_uint(f);
    unsigned r = (u + 0x7FFFu + ((u >> 16) & 1u)) >> 16;  // RNE
    return (unsigned short)r;
}

// ---------------------------------------------------------------------------
__global__ void init_colmap_kernel(int* __restrict__ cm, int IC) {
    int i = blockIdx.x * 256 + threadIdx.x;
    if (i < IC) cm[i] = -1;
}

__global__ void scatter_colmap_kernel(const int* __restrict__ idx,
                                      int* __restrict__ cm, int n) {
    int j = blockIdx.x * 256 + threadIdx.x;
    if (j < n) atomicMax(&cm[idx[j]], j);
}

// ---------------------------------------------------------------------------
__global__ void quant_weight_kernel(const float* __restrict__ w,
                                    const float* __restrict__ ow,
                                    const int* __restrict__ cm,
                                    unsigned short* __restrict__ wq,
                                    int IC, int n_out) {
    __shared__ float red[8];
    const int o = blockIdx.x;
    const int t = threadIdx.x;
    const int lane = t & 63, wid = t >> 6;

    const float4* row4 = (const float4*)(w + (size_t)o * IC);
    float4 v[4];
    float s = 0.f;
#pragma unroll
    for (int j = 0; j < 4; ++j) {
        v[j] = row4[t + j * 256];
        s += v[j].x + v[j].y + v[j].z + v[j].w;
    }
#pragma unroll
    for (int off = 32; off; off >>= 1) s += __shfl_down(s, off);
    if (lane == 0) red[wid] = s;
    __syncthreads();
    const float mean = (red[0] + red[1] + red[2] + red[3]) / (float)IC;

    float a = 0.f;
#pragma unroll
    for (int j = 0; j < 4; ++j)
        a += fabsf(v[j].x - mean) + fabsf(v[j].y - mean) +
             fabsf(v[j].z - mean) + fabsf(v[j].w - mean);
#pragma unroll
    for (int off = 32; off; off >>= 1) a += __shfl_down(a, off);
    if (lane == 0) red[4 + wid] = a;
    __syncthreads();
    const float scale = (red[4] + red[5] + red[6] + red[7]) / (float)IC;

    const size_t base = (size_t)o * IC;
    const float* owr = ow + (size_t)o * n_out;
#pragma unroll
    for (int j = 0; j < 4; ++j) {
        const int c0 = (t + j * 256) * 4;
        float ee[4] = {v[j].x, v[j].y, v[j].z, v[j].w};
        us4 q4;
#pragma unroll
        for (int ei = 0; ei < 4; ++ei) {
            float c = ee[ei] - mean;
            float q = c > 0.f ? scale : (c < 0.f ? -scale : 0.f);
            int m = cm[c0 + ei];
            if (m >= 0) q = owr[m];
            q4[ei] = f2bf(q);
        }
        *(us4*)&wq[base + c0] = q4;
    }
}

// ---------------------------------------------------------------------------
__global__ void cast_x_kernel(const float4* __restrict__ x4,
                              us8* __restrict__ xb, long n8) {
    long i = (long)blockIdx.x * blockDim.x + threadIdx.x;
    const long stride = (long)gridDim.x * blockDim.x;
    for (; i < n8; i += stride) {
        float4 a = x4[i * 2], b = x4[i * 2 + 1];
        us8 o;
        o[0] = f2bf(a.x); o[1] = f2bf(a.y); o[2] = f2bf(a.z); o[3] = f2bf(a.w);
        o[4] = f2bf(b.x); o[5] = f2bf(b.y); o[6] = f2bf(b.z); o[7] = f2bf(b.w);
        xb[i] = o;
    }
}

// ---------------------------------------------------------------------------
// GEMM: C[M,N] = A[M,K] * B[N,K]^T + bias.  512 thr = 8 waves (2M x 4N),
// per-wave 128x64 = 8(mi) x 4(ni) frags of 16x16, mfma_f32_16x16x32_bf16.
// LDS: lds[buf4][mat2][256][32] bf16 (strides 16384 / 8192 elems), 128 KiB.
// Slot-XOR swizzle (measured 0 conflicts).
// Per phase: { STAGE ; [vmcnt(4) at P1] ; s_barrier ;
//              issue NEXT phase's ds_reads ; setprio(1) ; 16 MFMA (current
//              regs, read last phase) ; setprio(0) ; s_barrier }
// Buf validity for early reads: vmcnt(4) leaves only current tile's stages
// in flight, so buf(t+1) (staged during t-2) is complete at tile t's P1.
// ---------------------------------------------------------------------------
#define GLDS(src, dst) __builtin_amdgcn_global_load_lds( \
    (const __attribute__((address_space(1))) void*)(src), \
    (__attribute__((address_space(3))) void*)(dst), 16, 0, 0)

// Stage A / B of a future tile into buffer BUFS; TOFF = compile-time element
// offset selecting the tile within the current pointer window.
#define STAGEA(BUFS, TOFF) do {                                               \
    GLDS(aP0 + (TOFF), &lds[(BUFS) * 16384 + (wid * 16) * 32]);               \
    GLDS(aP1 + (TOFF), &lds[(BUFS) * 16384 + (128 + wid * 16) * 32]);         \
  } while (0)
#define STAGEB(BUFS, TOFF) do {                                               \
    GLDS(bP0 + (TOFF), &lds[(BUFS) * 16384 + 8192 + (wid * 16) * 32]);        \
    GLDS(bP1 + (TOFF), &lds[(BUFS) * 16384 + 8192 + (128 + wid * 16) * 32]);  \
  } while (0)

// A-fragment reads (4 x ds_read_b128) for fragment-half FH from buf B_
#define RDA(AF, FH, B_) do {                                                  \
    const unsigned short* pa_ = &lds[(B_) * 16384];                           \
    _Pragma("unroll")                                                         \
    for (int j_ = 0; j_ < 4; ++j_)                                            \
      AF[j_] = *(const bf16x8*)&pa_[(wr * 128 + ((FH) * 4 + j_) * 16 + l15) * 32 + sl8]; \
  } while (0)

// B-fragment reads (4 x ds_read_b128) from buf B_
#define RDB(BF, B_) do {                                                      \
    const unsigned short* pb_ = &lds[(B_) * 16384 + 8192];                    \
    _Pragma("unroll")                                                         \
    for (int j_ = 0; j_ < 4; ++j_)                                            \
      BF[j_] = *(const bf16x8*)&pb_[(wc * 64 + j_ * 16 + l15) * 32 + sl8];    \
  } while (0)

#define MM16(AF, BF, FH) do {                                                 \
    _Pragma("unroll")                                                         \
    for (int mi_ = 0; mi_ < 4; ++mi_)                                         \
      _Pragma("unroll")                                                       \
      for (int ni_ = 0; ni_ < 4; ++ni_)                                       \
        acc[(FH) * 4 + mi_][ni_] = __builtin_amdgcn_mfma_f32_16x16x32_bf16(   \
            AF[mi_], BF[ni_], acc[(FH) * 4 + mi_][ni_], 0, 0, 0);             \
  } while (0)

// Phase: stage ; optional vmcnt(4) ; barrier ; NEXT-phase reads ; MFMA current.
#define PH(STCALL, VM, RDCALL, AFU, BFU, FH) do {                             \
    STCALL;                                                                   \
    if (VM) asm volatile("s_waitcnt vmcnt(4)" ::: "memory");                  \
    __builtin_amdgcn_s_barrier();                                             \
    RDCALL;                                                                   \
    __builtin_amdgcn_s_setprio(1);                                            \
    MM16(AFU, BFU, FH);                                                       \
    __builtin_amdgcn_s_setprio(0);                                            \
    __builtin_amdgcn_s_barrier();                                             \
  } while (0)

__global__ __launch_bounds__(512, 2) void gemm_8phase_kernel(
    const unsigned short* __restrict__ A,   // [M,K] bf16 bits
    const unsigned short* __restrict__ B,   // [N,K] bf16 bits
    const float* __restrict__ bias,         // [N]
    float* __restrict__ C,                  // [M,N] f32
    int M, int N, int K, int NBN) {
    extern __shared__ unsigned short lds[];  // 131072 B = 4 x 32 KiB buffers

    const int t = threadIdx.x;
    const int wid = t >> 6, lane = t & 63;
    const int l15 = lane & 15;
    const int sl8 = (((lane >> 4) ^ ((lane >> 1) & 3)) & 3) * 8;  // read slot
    const int wr = wid >> 2;                  // 0..1  (M half)
    const int wc = wid & 3;                   // 0..3  (N quarter)
    const int stg_row = wid * 16 + (lane >> 2);
    const int stg_col = (((lane & 3) ^ ((lane >> 3) & 3)) & 3) * 8;

    // bijective XCD swizzle
    const int nwg = gridDim.x;
    const int bid = blockIdx.x;
    const int q = nwg >> 3, r = nwg & 7;
    const int xcd = bid & 7, off = bid >> 3;
    const int swz = (xcd < r ? xcd * (q + 1) : r * (q + 1) + (xcd - r) * q) + off;
    const int bm = swz / NBN, bn = swz % NBN;

    const unsigned short* Ablk = A + (size_t)(bm * 256) * K;
    const unsigned short* Bblk = B + (size_t)(bn * 256) * K;

    // advancing per-thread staging pointers (tile window base = k-offset 0)
    const unsigned short* aP0 = Ablk + (size_t)stg_row * K + stg_col;
    const unsigned short* aP1 = aP0 + (size_t)128 * K;
    const unsigned short* bP0 = Bblk + (size_t)stg_row * K + stg_col;
    const unsigned short* bP1 = bP0 + (size_t)128 * K;

    f32x4 acc[8][4] = {};
    bf16x8 af0[4], af1[4], bf0[4], bf1[4];

    // ---- prologue: stage tiles 0,1,2 -> bufs 0,1,2; wait tile0; pre-read ----
    STAGEA(0, 0);  STAGEB(0, 0);
    STAGEA(1, 32); STAGEB(1, 32);
    STAGEA(2, 64); STAGEB(2, 64);
    aP0 += 96; aP1 += 96; bP0 += 96; bP1 += 96;   // window now at tile 3
    asm volatile("s_waitcnt vmcnt(8)" ::: "memory");
    __builtin_amdgcn_s_barrier();
    RDB(bf0, 0);
    RDA(af0, 0, 0);

    // 128 tiles = 32 iterations x 4 tiles. During tile t stage tile t+3.
    // Trailing iterations stage/read a few tiles past K -- values land in
    // adjacent ws regions (mapped) and are never consumed.
    for (int it = 0; it < 32; ++it) {
        // T0 (read buf0, B in bf0)
        PH(STAGEA(3, 0),  false, RDA(af1, 1, 0),                  af0, bf0, 0);
        PH(STAGEB(3, 0),  true,  { RDB(bf1, 1); RDA(af0, 0, 1); }, af1, bf0, 1);
        // T1 (buf1, bf1)
        PH(STAGEA(0, 32), false, RDA(af1, 1, 1),                  af0, bf1, 0);
        PH(STAGEB(0, 32), true,  { RDB(bf0, 2); RDA(af0, 0, 2); }, af1, bf1, 1);
        // T2 (buf2, bf0)
        PH(STAGEA(1, 64), false, RDA(af1, 1, 2),                  af0, bf0, 0);
        PH(STAGEB(1, 64), true,  { RDB(bf1, 3); RDA(af0, 0, 3); }, af1, bf0, 1);
        // T3 (buf3, bf1)
        PH(STAGEA(2, 96), false, RDA(af1, 1, 3),                  af0, bf1, 0);
        PH(STAGEB(2, 96), true,  { RDB(bf0, 0); RDA(af0, 0, 0); }, af1, bf1, 1);
        aP0 += 128; aP1 += 128; bP0 += 128; bP1 += 128;
    }

    // ---- epilogue: bias + store (C/D: col=lane&15, row=(lane>>4)*4+r) ----
    float bv[4];
#pragma unroll
    for (int ni = 0; ni < 4; ++ni)
        bv[ni] = bias[bn * 256 + wc * 64 + ni * 16 + l15];

    const int crow0 = bm * 256 + wr * 128;
    const int ccol = bn * 256 + wc * 64 + l15;
#pragma unroll
    for (int mi = 0; mi < 8; ++mi) {
#pragma unroll
        for (int rr = 0; rr < 4; ++rr) {
            const int row = crow0 + mi * 16 + (lane >> 4) * 4 + rr;
            float* Crow = C + (size_t)row * N;
#pragma unroll
            for (int ni = 0; ni < 4; ++ni)
                Crow[ccol + ni * 16] = acc[mi][ni][rr] + bv[ni];
        }
    }
}

// ---------------------------------------------------------------------------
extern "C" void kernel_launch(void* const* d_in, const int* in_sizes, int n_in,
                              void* d_out, int out_size, void* d_ws, size_t ws_size,
                              hipStream_t stream) {
    const float* x      = (const float*)d_in[0];
    const float* weight = (const float*)d_in[1];
    const float* bias   = (const float*)d_in[2];
    const float* ow     = (const float*)d_in[3];
    const int*   idx    = (const int*)d_in[4];

    const int OC    = in_sizes[2];
    const int n_out = in_sizes[4];
    const int IC    = in_sizes[1] / OC;
    const int M     = in_sizes[0] / IC;
    float* out = (float*)d_out;

    char* ws = (char*)d_ws;
    unsigned short* wq = (unsigned short*)ws;                              // OC*IC bf16
    unsigned short* xb = (unsigned short*)(ws + (size_t)OC * IC * 2);      // M*IC bf16
    int* cm = (int*)(ws + (size_t)OC * IC * 2 + (size_t)M * IC * 2);       // IC ints

    init_colmap_kernel<<<(IC + 255) / 256, 256, 0, stream>>>(cm, IC);
    scatter_colmap_kernel<<<(n_out + 255) / 256, 256, 0, stream>>>(idx, cm, n_out);
    quant_weight_kernel<<<OC, 256, 0, stream>>>(weight, ow, cm, wq, IC, n_out);

    const long n8 = (long)M * IC / 8;
    cast_x_kernel<<<2048, 256, 0, stream>>>((const float4*)x, (us8*)xb, n8);

    hipFuncSetAttribute((const void*)gemm_8phase_kernel,
                        hipFuncAttributeMaxDynamicSharedMemorySize, 131072);
    const int NBM = M / 256, NBN = OC / 256;
    gemm_8phase_kernel<<<dim3(NBM * NBN), dim3(512), 131072, stream>>>(
        xb, wq, bias, out, M, OC, IC, NBN);
}

// Round 9
// 202.698 us; speedup vs baseline: 2.5704x; 1.4384x over previous
//
#include <hip/hip_runtime.h>
#include <hip/hip_bf16.h>

// ---------------------------------------------------------------------------
// OutliersQLinearColumn: out = x @ w^T + bias,  w = s_o*sign(weight-mean_o)
// with fp32 outlier columns scattered in (last-wins).
// Round 9: i8 MFMA path (2x bf16 rate). Factor scales out:
//   out[m,o] = (s_o*D_m/8) * sum_k qx[m,k]*qw[o,k] + bias_o,  K2 = 4096+256
//   k<4096   : qw = 8*sign(centered)  (exact),  qx = rint(x/D_m), D_m=rowmax/127
//   k>=4096  : outlier correction: winner slot j -> qw = rint(8*(ow - s*sign)/s)
//              (clamped +-127), qx = qx[m, idx_j]; losers/pad -> qw = 0.
// GEMM skeleton = R7's proven structure byte-for-byte (64-B LDS rows,
// slot-XOR swizzle = 0 conflicts, 4 bufs, vmcnt(8), 2 phases/tile).
// ---------------------------------------------------------------------------

typedef __attribute__((ext_vector_type(4))) int i32x4;

// ---------------------------------------------------------------------------
// col_map: winning outlier slot per column (last-wins), or -1.
// ---------------------------------------------------------------------------
__global__ void init_colmap_kernel(int* __restrict__ cm, int IC) {
    int i = blockIdx.x * 256 + threadIdx.x;
    if (i < IC) cm[i] = -1;
}

__global__ void scatter_colmap_kernel(const int* __restrict__ idx,
                                      int* __restrict__ cm, int n) {
    int j = blockIdx.x * 256 + threadIdx.x;
    if (j < n) atomicMax(&cm[idx[j]], j);
}

// ---------------------------------------------------------------------------
// Weight row -> mean, scale s, and qw = 8*sign(centered) (i8). One row/block.
// ---------------------------------------------------------------------------
__global__ void quant_sign_kernel(const float* __restrict__ w,
                                  signed char* __restrict__ qw,
                                  float* __restrict__ sArr,
                                  float* __restrict__ meanArr,
                                  int IC, int K2) {
    __shared__ float red[8];
    const int o = blockIdx.x;
    const int t = threadIdx.x;
    const int lane = t & 63, wid = t >> 6;

    const float4* row4 = (const float4*)(w + (size_t)o * IC);
    float4 v[4];
    float s = 0.f;
#pragma unroll
    for (int j = 0; j < 4; ++j) {
        v[j] = row4[t + j * 256];
        s += v[j].x + v[j].y + v[j].z + v[j].w;
    }
#pragma unroll
    for (int off = 32; off; off >>= 1) s += __shfl_down(s, off);
    if (lane == 0) red[wid] = s;
    __syncthreads();
    const float mean = (red[0] + red[1] + red[2] + red[3]) / (float)IC;

    float a = 0.f;
#pragma unroll
    for (int j = 0; j < 4; ++j)
        a += fabsf(v[j].x - mean) + fabsf(v[j].y - mean) +
             fabsf(v[j].z - mean) + fabsf(v[j].w - mean);
#pragma unroll
    for (int off = 32; off; off >>= 1) a += __shfl_down(a, off);
    if (lane == 0) red[4 + wid] = a;
    __syncthreads();
    const float scale = (red[4] + red[5] + red[6] + red[7]) / (float)IC;

    if (t == 0) { sArr[o] = scale; meanArr[o] = mean; }

    const size_t base = (size_t)o * K2;
#pragma unroll
    for (int j = 0; j < 4; ++j) {
        const int c0 = (t + j * 256) * 4;
        float ee[4] = {v[j].x, v[j].y, v[j].z, v[j].w};
        int pack = 0;
#pragma unroll
        for (int ei = 0; ei < 4; ++ei) {
            float c = ee[ei] - mean;
            int q = c > 0.f ? 8 : (c < 0.f ? -8 : 0);
            pack |= (q & 0xff) << (ei * 8);
        }
        *(int*)(qw + base + c0) = pack;
    }
}

// ---------------------------------------------------------------------------
// Correction columns of qw: j in [0,256). Winner slot -> quantized residual.
// ---------------------------------------------------------------------------
__global__ void corr_w_kernel(const float* __restrict__ w,
                              const float* __restrict__ ow,
                              const int* __restrict__ idx,
                              const int* __restrict__ cm,
                              const float* __restrict__ sArr,
                              const float* __restrict__ meanArr,
                              signed char* __restrict__ qw,
                              int IC, int K2, int n_out) {
    const int o = blockIdx.x;
    const int j = threadIdx.x;          // 0..255
    signed char q = 0;
    if (j < n_out) {
        const int c = idx[j];
        if (cm[c] == j) {
            const float s = sArr[o];
            const float cen = w[(size_t)o * IC + c] - meanArr[o];
            const float sg = cen > 0.f ? 1.f : (cen < 0.f ? -1.f : 0.f);
            const float wc = ow[(size_t)o * n_out + j] - s * sg;
            float qf = rintf(8.f * wc / s);
            qf = fminf(127.f, fmaxf(-127.f, qf));
            q = (signed char)(int)qf;
        }
    }
    qw[(size_t)o * K2 + IC + j] = q;
}

// ---------------------------------------------------------------------------
// x row -> D_m = rowmax/127 and qx = rint(x/D_m). One row/block (256 thr).
// ---------------------------------------------------------------------------
__global__ void quant_x_kernel(const float4* __restrict__ x4,
                               signed char* __restrict__ qx,
                               float* __restrict__ rdel,
                               int IC, int K2) {
    __shared__ float red[4];
    __shared__ float bmax;
    const int m = blockIdx.x;
    const int t = threadIdx.x;
    const int lane = t & 63, wid = t >> 6;

    const float4* row4 = x4 + (size_t)m * (IC / 4);
    float4 v[4];
    float mx = 0.f;
#pragma unroll
    for (int j = 0; j < 4; ++j) {
        v[j] = row4[t + j * 256];
        mx = fmaxf(mx, fmaxf(fmaxf(fabsf(v[j].x), fabsf(v[j].y)),
                             fmaxf(fabsf(v[j].z), fabsf(v[j].w))));
    }
#pragma unroll
    for (int off = 32; off; off >>= 1) mx = fmaxf(mx, __shfl_down(mx, off));
    if (lane == 0) red[wid] = mx;
    __syncthreads();
    if (t == 0) {
        float m0 = fmaxf(fmaxf(red[0], red[1]), fmaxf(red[2], red[3]));
        bmax = m0;
        rdel[m] = m0 / 127.f;
    }
    __syncthreads();
    const float inv = 127.f / bmax;

    const size_t base = (size_t)m * K2;
#pragma unroll
    for (int j = 0; j < 4; ++j) {
        const int c0 = (t + j * 256) * 4;
        float ee[4] = {v[j].x, v[j].y, v[j].z, v[j].w};
        int pack = 0;
#pragma unroll
        for (int ei = 0; ei < 4; ++ei) {
            int q = (int)rintf(ee[ei] * inv);
            pack |= (q & 0xff) << (ei * 8);
        }
        *(int*)(qx + base + c0) = pack;
    }
}

// ---------------------------------------------------------------------------
// Gather correction qx columns: qx[m, IC+j] = qx[m, idx_j] (j<n_out) else 0.
// ---------------------------------------------------------------------------
__global__ void gather_xo_kernel(signed char* __restrict__ qx,
                                 const int* __restrict__ idx,
                                 int IC, int K2, int n_out) {
    const int m = blockIdx.x;
    const int j = threadIdx.x;          // 0..255
    signed char v = 0;
    if (j < n_out) v = qx[(size_t)m * K2 + idx[j]];
    qx[(size_t)m * K2 + IC + j] = v;
}

// ---------------------------------------------------------------------------
// i8 GEMM: acc[m,o] = sum_k qx[m,k]*qw[o,k];  out = acc*(s_o*D_m/8) + bias_o.
// 512 thr = 8 waves (2M x 4N), per-wave 128x64 = 8(mi) x 4(ni) frags 16x16,
// mfma_i32_16x16x64_i8 (one MFMA eats a full BK=64 K-tile slice).
// LDS: lds[buf4][mat2][256 rows][64 B] (strides 32768/16384/64 B), 128 KiB.
// Slot-XOR swizzle on 16-B granules (identical byte layout to R7, 0 confl).
// Per tile: P0 {RDB(4)+RDA(FH0)(4); stage A(t+3); barrier; 16 MFMA; barrier}
//           P1 {RDA(FH1)(4);        stage B(t+3); vmcnt(8); barrier; 16 MFMA; barrier}
// ---------------------------------------------------------------------------
#define GLDS(src, dst) __builtin_amdgcn_global_load_lds( \
    (const __attribute__((address_space(1))) void*)(src), \
    (__attribute__((address_space(3))) void*)(dst), 16, 0, 0)

// Stage matrix MAT (0=A,1=B) of the BK64 tile at byte k-offset knB into bufS.
#define STAGE64(MAT, bufS, knB) do {                                          \
    const signed char* gsrc_ = (MAT) ? Bblk : Ablk;                           \
    _Pragma("unroll")                                                         \
    for (int rr_ = 0; rr_ < 2; ++rr_) {                                       \
      GLDS(gsrc_ + (size_t)(rr_ * 128 + stg_row) * K2 + (knB) + stg_col,      \
           &ldsb[(bufS) * 32768 + (MAT) * 16384 + (rr_ * 128 + wid * 16) * 64]); \
    } } while (0)

// A-fragment reads (4 x ds_read_b128) for fragment-half FH from buf B_
#define RDA(AF, FH, B_) do {                                                  \
    const signed char* pa_ = &ldsb[(B_) * 32768];                             \
    _Pragma("unroll")                                                         \
    for (int j_ = 0; j_ < 4; ++j_)                                            \
      AF[j_] = *(const i32x4*)&pa_[(wr * 128 + ((FH) * 4 + j_) * 16 + l15) * 64 + slB]; \
  } while (0)

// B-fragment reads (4 x ds_read_b128) from buf B_
#define RDB(BF, B_) do {                                                      \
    const signed char* pb_ = &ldsb[(B_) * 32768 + 16384];                     \
    _Pragma("unroll")                                                         \
    for (int j_ = 0; j_ < 4; ++j_)                                            \
      BF[j_] = *(const i32x4*)&pb_[(wc * 64 + j_ * 16 + l15) * 64 + slB];     \
  } while (0)

#define MM16(FH) do {                                                         \
    _Pragma("unroll")                                                         \
    for (int mi_ = 0; mi_ < 4; ++mi_)                                         \
      _Pragma("unroll")                                                       \
      for (int ni_ = 0; ni_ < 4; ++ni_)                                       \
        acc[(FH) * 4 + mi_][ni_] = __builtin_amdgcn_mfma_i32_16x16x64_i8(     \
            afr[mi_], bfr[ni_], acc[(FH) * 4 + mi_][ni_], 0, 0, 0);           \
  } while (0)

#define PH64(FH, DOBF, STMAT, VM, bufR, bufS, knB) do {                       \
    if (DOBF) RDB(bfr, bufR);                                                 \
    RDA(afr, FH, bufR);                                                       \
    STAGE64(STMAT, bufS, knB);                                                \
    if (VM) asm volatile("s_waitcnt vmcnt(8)" ::: "memory");                  \
    __builtin_amdgcn_s_barrier();                                             \
    __builtin_amdgcn_s_setprio(1);                                            \
    MM16(FH);                                                                 \
    __builtin_amdgcn_s_setprio(0);                                            \
    __builtin_amdgcn_s_barrier();                                             \
  } while (0)

#define KT64(bufR, bufS, knB) do {                                            \
    PH64(0, true,  0, false, bufR, bufS, knB);                                \
    PH64(1, false, 1, true,  bufR, bufS, knB);                                \
  } while (0)

__global__ __launch_bounds__(512, 2) void gemm_i8_kernel(
    const signed char* __restrict__ Aq,   // [M, K2] i8
    const signed char* __restrict__ Bq,   // [OC, K2] i8
    const float* __restrict__ bias,       // [OC]
    const float* __restrict__ sArr,       // [OC]
    const float* __restrict__ rdel,       // [M]
    float* __restrict__ C,                // [M, OC] f32
    int M, int N, int K2, int NBN) {
    extern __shared__ signed char ldsb[];  // 131072 B = 4 x 32 KiB buffers

    const int t = threadIdx.x;
    const int wid = t >> 6, lane = t & 63;
    const int l15 = lane & 15;
    const int slB = (((lane >> 4) ^ ((lane >> 1) & 3)) & 3) * 16;  // read slot (bytes)
    const int wr = wid >> 2;                  // 0..1  (M half)
    const int wc = wid & 3;                   // 0..3  (N quarter)
    const int stg_row = wid * 16 + (lane >> 2);
    const int stg_col = (((lane & 3) ^ ((lane >> 3) & 3)) & 3) * 16;  // bytes

    // bijective XCD swizzle
    const int nwg = gridDim.x;
    const int bid = blockIdx.x;
    const int q = nwg >> 3, r = nwg & 7;
    const int xcd = bid & 7, off = bid >> 3;
    const int swz = (xcd < r ? xcd * (q + 1) : r * (q + 1) + (xcd - r) * q) + off;
    const int bm = swz / NBN, bn = swz % NBN;

    const signed char* Ablk = Aq + (size_t)(bm * 256) * K2;
    const signed char* Bblk = Bq + (size_t)(bn * 256) * K2;

    i32x4 acc[8][4] = {};
    i32x4 afr[4], bfr[4];

    // ---- prologue: stage tiles 0,1,2 -> bufs 0,1,2; wait tile0 ----
    STAGE64(0, 0, 0);    STAGE64(1, 0, 0);
    STAGE64(0, 1, 64);   STAGE64(1, 1, 64);
    STAGE64(0, 2, 128);  STAGE64(1, 2, 128);
    asm volatile("s_waitcnt vmcnt(8)" ::: "memory");
    __builtin_amdgcn_s_barrier();

    // NT = K2/64 = 68 tiles = 17 iterations x 4. During tile t stage t+3.
    for (int it = 0; it < 17; ++it) {
        const int tt = it * 4;
        const int k3 = (tt + 3) * 64;                        // <= 67*64, live
        const int k4 = (tt + 4 < 68) ? (tt + 4) * 64 : 0;    // dead at end
        const int k5 = (tt + 5 < 68) ? (tt + 5) * 64 : 0;
        const int k6 = (tt + 6 < 68) ? (tt + 6) * 64 : 0;
        KT64(0, 3, k3);
        KT64(1, 0, k4);
        KT64(2, 1, k5);
        KT64(3, 2, k6);
    }

    // ---- epilogue: out = acc*(s_o*D_m/8) + bias ----
    // C/D layout: col = lane&15, row = (lane>>4)*4 + reg
    float sv[4], bv[4];
#pragma unroll
    for (int ni = 0; ni < 4; ++ni) {
        const int col = bn * 256 + wc * 64 + ni * 16 + l15;
        sv[ni] = sArr[col] * 0.125f;
        bv[ni] = bias[col];
    }

    const int crow0 = bm * 256 + wr * 128;
    const int ccol = bn * 256 + wc * 64 + l15;
#pragma unroll
    for (int mi = 0; mi < 8; ++mi) {
#pragma unroll
        for (int rr = 0; rr < 4; ++rr) {
            const int row = crow0 + mi * 16 + (lane >> 4) * 4 + rr;
            const float rd = rdel[row];
            float* Crow = C + (size_t)row * N;
#pragma unroll
            for (int ni = 0; ni < 4; ++ni)
                Crow[ccol + ni * 16] =
                    (float)acc[mi][ni][rr] * (sv[ni] * rd) + bv[ni];
        }
    }
}

// ---------------------------------------------------------------------------
extern "C" void kernel_launch(void* const* d_in, const int* in_sizes, int n_in,
                              void* d_out, int out_size, void* d_ws, size_t ws_size,
                              hipStream_t stream) {
    const float* x      = (const float*)d_in[0];
    const float* weight = (const float*)d_in[1];
    const float* bias   = (const float*)d_in[2];
    const float* ow     = (const float*)d_in[3];
    const int*   idx    = (const int*)d_in[4];

    const int OC    = in_sizes[2];
    const int n_out = in_sizes[4];
    const int IC    = in_sizes[1] / OC;      // 4096
    const int M     = in_sizes[0] / IC;      // 8192
    const int K2    = IC + 256;              // 4352
    float* out = (float*)d_out;

    char* ws = (char*)d_ws;
    signed char* qx = (signed char*)ws;                                 // M*K2
    signed char* qw = (signed char*)(ws + (size_t)M * K2);              // OC*K2
    float* sArr   = (float*)(ws + (size_t)M * K2 + (size_t)OC * K2);    // OC
    float* meanArr= sArr + OC;                                          // OC
    float* rdel   = meanArr + OC;                                       // M
    int*   cm     = (int*)(rdel + M);                                   // IC

    init_colmap_kernel<<<(IC + 255) / 256, 256, 0, stream>>>(cm, IC);
    scatter_colmap_kernel<<<(n_out + 255) / 256, 256, 0, stream>>>(idx, cm, n_out);
    quant_sign_kernel<<<OC, 256, 0, stream>>>(weight, qw, sArr, meanArr, IC, K2);
    corr_w_kernel<<<OC, 256, 0, stream>>>(weight, ow, idx, cm, sArr, meanArr,
                                          qw, IC, K2, n_out);
    quant_x_kernel<<<M, 256, 0, stream>>>((const float4*)x, qx, rdel, IC, K2);
    gather_xo_kernel<<<M, 256, 0, stream>>>(qx, idx, IC, K2, n_out);

    hipFuncSetAttribute((const void*)gemm_i8_kernel,
                        hipFuncAttributeMaxDynamicSharedMemorySize, 131072);
    const int NBM = M / 256, NBN = OC / 256;
    gemm_i8_kernel<<<dim3(NBM * NBN), dim3(512), 131072, stream>>>(
        qx, qw, bias, sArr, rdel, out, M, OC, K2, NBN);
}